// Round 2
// baseline (1000.605 us; speedup 1.0000x reference)
//
#include <hip/hip_runtime.h>

#define ZD 21
#define YD 256
#define XD 256
#define BD 2
#define NCIN 16
#define NC1 32
#define NC2 64
#define BN_EPS 1e-3f

__global__ __launch_bounds__(256) void scatter_grid_k(const int* __restrict__ coors,
                                                      int* __restrict__ grid, int n) {
    int i = blockIdx.x * 256 + threadIdx.x;
    if (i >= n) return;
    const int4 c = ((const int4*)coors)[i];   // [b, z, y, x]
    const int lin = ((c.x * ZD + c.y) * YD + c.z) * XD + c.w;
    grid[lin] = i;
}

// wave = 64 output voxels; lanes 0-31 = channels (lanes 32-63 duplicate).
// Per offset k: lane-parallel grid lookup + ballot -> wave-uniform mask scan.
__global__ __launch_bounds__(256) void conv1_k(
    const float* __restrict__ feat, const int* __restrict__ coors,
    const float* __restrict__ W1,
    const float* __restrict__ g1, const float* __restrict__ b1,
    const float* __restrict__ m1, const float* __restrict__ v1,
    const int* __restrict__ grid, float* __restrict__ f1, int n) {
    __shared__ float4 sWb[2][NCIN * NC1 / 4];
    const int tid = threadIdx.x;
    const int lane = tid & 63;
    const int c = lane & 31;
    const int vbase = blockIdx.x * 256 + (tid >> 6) * 64;

    int bb = 0, z0 = 0, y0 = 0, x0 = 0;
    const bool vok = (vbase + lane) < n;
    if (vok) {
        const int4 cc = ((const int4*)coors)[vbase + lane];
        bb = cc.x; z0 = cc.y; y0 = cc.z; x0 = cc.w;
    }

    // stage k=0 (512 floats = 128 float4; 256 threads -> guard)
    if (tid < 128) sWb[0][tid] = ((const float4*)W1)[tid];

    float acc[64];
#pragma unroll
    for (int j = 0; j < 64; ++j) acc[j] = 0.f;

    for (int k = 0; k < 27; ++k) {
        __syncthreads();
        if (k + 1 < 27 && tid < 128)
            sWb[(k + 1) & 1][tid] = ((const float4*)(W1 + (k + 1) * NCIN * NC1))[tid];

        int idx = -1;
        {
            const int z = z0 + (k / 9) - 1;
            const int y = y0 + ((k / 3) % 3) - 1;
            const int x = x0 + (k % 3) - 1;
            if (vok && (unsigned)z < ZD && (unsigned)y < YD && (unsigned)x < XD)
                idx = grid[((bb * ZD + z) * YD + y) * XD + x];
        }
        const unsigned long long mask = __ballot(idx >= 0);

        const float* swk = (const float*)sWb[k & 1];
        float w[NCIN];
#pragma unroll
        for (int ci = 0; ci < NCIN; ++ci) w[ci] = swk[ci * NC1 + c];

#pragma unroll
        for (int j = 0; j < 64; ++j) {
            if (mask & (1ull << j)) {
                const int id = __shfl(idx, j);
                const float4* fr = (const float4*)(feat + (size_t)id * NCIN);
                const float4 a = fr[0], b = fr[1], cq = fr[2], d = fr[3];
                float t0 = fmaf(a.x, w[0], fmaf(a.y, w[1], fmaf(a.z, w[2], a.w * w[3])));
                float t1 = fmaf(b.x, w[4], fmaf(b.y, w[5], fmaf(b.z, w[6], b.w * w[7])));
                float t2 = fmaf(cq.x, w[8], fmaf(cq.y, w[9], fmaf(cq.z, w[10], cq.w * w[11])));
                float t3 = fmaf(d.x, w[12], fmaf(d.y, w[13], fmaf(d.z, w[14], d.w * w[15])));
                acc[j] += (t0 + t1) + (t2 + t3);
            }
        }
    }

    const float sc = g1[c] * rsqrtf(v1[c] + BN_EPS);
    const float sb = b1[c] - m1[c] * sc;
#pragma unroll
    for (int j = 0; j < 64; ++j) {
        const int vi = vbase + j;
        if (lane < 32 && vi < n)
            f1[(size_t)vi * NC1 + c] = fmaxf(fmaf(acc[j], sc, sb), 0.f);
    }
}

// wave = 64 output voxels; lane = output channel (64).
__global__ __launch_bounds__(256) void conv2_k(
    const float* __restrict__ f1, const int* __restrict__ ocoors,
    const float* __restrict__ W2,
    const float* __restrict__ g2, const float* __restrict__ b2,
    const float* __restrict__ m2, const float* __restrict__ v2,
    const int* __restrict__ grid, float* __restrict__ out, int m) {
    __shared__ float4 sWb[2][NC1 * NC2 / 4];
    const int tid = threadIdx.x;
    const int lane = tid & 63;
    const int vbase = blockIdx.x * 256 + (tid >> 6) * 64;

    int bb = 0, z0 = 0, y0 = 0, x0 = 0;
    const bool vok = (vbase + lane) < m;
    if (vok) {
        const int4 cc = ((const int4*)ocoors)[vbase + lane];
        bb = cc.x; z0 = cc.y * 2; y0 = cc.z * 2 - 1; x0 = cc.w * 2 - 1;
    }

    // stage k=0: 2048 floats = 512 float4; 2 per thread
    sWb[0][tid * 2] = ((const float4*)W2)[tid * 2];
    sWb[0][tid * 2 + 1] = ((const float4*)W2)[tid * 2 + 1];

    float acc[64];
#pragma unroll
    for (int j = 0; j < 64; ++j) acc[j] = 0.f;

    for (int k = 0; k < 27; ++k) {
        __syncthreads();
        if (k + 1 < 27) {
            const float4* src = (const float4*)(W2 + (k + 1) * NC1 * NC2);
            float4* dst = sWb[(k + 1) & 1];
            dst[tid * 2] = src[tid * 2];
            dst[tid * 2 + 1] = src[tid * 2 + 1];
        }

        int idx = -1;
        {
            const int z = z0 + k / 9;
            const int y = y0 + (k / 3) % 3;
            const int x = x0 + k % 3;
            if (vok && (unsigned)z < ZD && (unsigned)y < YD && (unsigned)x < XD)
                idx = grid[((bb * ZD + z) * YD + y) * XD + x];
        }
        const unsigned long long mask = __ballot(idx >= 0);

        const float* swk = (const float*)sWb[k & 1];
        float w[NC1];
#pragma unroll
        for (int ci = 0; ci < NC1; ++ci) w[ci] = swk[ci * NC2 + lane];

#pragma unroll
        for (int j = 0; j < 64; ++j) {
            if (mask & (1ull << j)) {
                const int id = __shfl(idx, j);
                const float4* fr = (const float4*)(f1 + (size_t)id * NC1);
                const float4 q0 = fr[0], q1 = fr[1], q2 = fr[2], q3 = fr[3];
                const float4 q4 = fr[4], q5 = fr[5], q6 = fr[6], q7 = fr[7];
                float t0 = fmaf(q0.x, w[0], fmaf(q0.y, w[1], fmaf(q0.z, w[2], fmaf(q0.w, w[3],
                           fmaf(q1.x, w[4], fmaf(q1.y, w[5], fmaf(q1.z, w[6], q1.w * w[7])))))));
                float t1 = fmaf(q2.x, w[8], fmaf(q2.y, w[9], fmaf(q2.z, w[10], fmaf(q2.w, w[11],
                           fmaf(q3.x, w[12], fmaf(q3.y, w[13], fmaf(q3.z, w[14], q3.w * w[15])))))));
                float t2 = fmaf(q4.x, w[16], fmaf(q4.y, w[17], fmaf(q4.z, w[18], fmaf(q4.w, w[19],
                           fmaf(q5.x, w[20], fmaf(q5.y, w[21], fmaf(q5.z, w[22], q5.w * w[23])))))));
                float t3 = fmaf(q6.x, w[24], fmaf(q6.y, w[25], fmaf(q6.z, w[26], fmaf(q6.w, w[27],
                           fmaf(q7.x, w[28], fmaf(q7.y, w[29], fmaf(q7.z, w[30], q7.w * w[31])))))));
                acc[j] += (t0 + t1) + (t2 + t3);
            }
        }
    }

    const float sc = g2[lane] * rsqrtf(v2[lane] + BN_EPS);
    const float sb = b2[lane] - m2[lane] * sc;
#pragma unroll
    for (int j = 0; j < 64; ++j) {
        const int vi = vbase + j;
        if (vi < m)
            out[(size_t)vi * NC2 + lane] = fmaxf(fmaf(acc[j], sc, sb), 0.f);
    }
}

// out_coors passthrough (as float values) + batch_size
__global__ __launch_bounds__(256) void tail_k(const int* __restrict__ oc,
                                              const int* __restrict__ bs,
                                              float* __restrict__ out, int m4) {
    int i = blockIdx.x * 256 + threadIdx.x;
    if (i < m4) out[i] = (float)oc[i];
    if (i == m4) out[m4] = (float)bs[0];
}

extern "C" void kernel_launch(void* const* d_in, const int* in_sizes, int n_in,
                              void* d_out, int out_size, void* d_ws, size_t ws_size,
                              hipStream_t stream) {
    const float* feat  = (const float*)d_in[0];
    const int*   coors = (const int*)d_in[1];
    const int*   ocoors= (const int*)d_in[2];
    const float* W1 = (const float*)d_in[3];
    const float* g1 = (const float*)d_in[4];
    const float* b1 = (const float*)d_in[5];
    const float* m1 = (const float*)d_in[6];
    const float* v1 = (const float*)d_in[7];
    const float* W2 = (const float*)d_in[8];
    const float* g2 = (const float*)d_in[9];
    const float* b2 = (const float*)d_in[10];
    const float* m2 = (const float*)d_in[11];
    const float* v2 = (const float*)d_in[12];
    const int*   bs = (const int*)d_in[13];

    const int n = in_sizes[0] / NCIN;
    const int m = in_sizes[2] / 4;

    const size_t GRID_N = (size_t)BD * ZD * YD * XD;
    int* grid = (int*)d_ws;
    float* f1 = (float*)((char*)d_ws + ((GRID_N * sizeof(int) + 255) & ~(size_t)255));

    hipMemsetAsync(grid, 0xFF, GRID_N * sizeof(int), stream);
    scatter_grid_k<<<(n + 255) / 256, 256, 0, stream>>>(coors, grid, n);
    conv1_k<<<(n + 255) / 256, 256, 0, stream>>>(feat, coors, W1, g1, b1, m1, v1, grid, f1, n);

    float* out = (float*)d_out;
    conv2_k<<<(m + 255) / 256, 256, 0, stream>>>(f1, ocoors, W2, g2, b2, m2, v2, grid, out, m);
    tail_k<<<(m * 4 + 1 + 255) / 256, 256, 0, stream>>>(ocoors, bs, out + (size_t)m * NC2, m * 4);
}

// Round 3
// 504.716 us; speedup vs baseline: 1.9825x; 1.9825x over previous
//
#include <hip/hip_runtime.h>

#define ZD 21
#define YD 256
#define XD 256
#define BD 2
#define NCIN 16
#define NC1 32
#define NC2 64
#define BN_EPS 1e-3f

__global__ __launch_bounds__(256) void scatter_grid_k(const int* __restrict__ coors,
                                                      int* __restrict__ grid, int n) {
    int i = blockIdx.x * 256 + threadIdx.x;
    if (i >= n) return;
    const int4 c = ((const int4*)coors)[i];   // [b, z, y, x]
    const int lin = ((c.x * ZD + c.y) * YD + c.z) * XD + c.w;
    grid[lin] = i;
}

// wave = 32 output voxels, 64 lanes = 32 channels x 2 ci-halves.
// lane = h*32 + c; h covers input channels [h*8, h*8+8). acc[32] partials,
// cross-half shfl_xor reduce at the end. Wave-uniform mask scan over hits.
__global__ __launch_bounds__(256, 6) void conv1_k(
    const float* __restrict__ feat, const int* __restrict__ coors,
    const float* __restrict__ W1,
    const float* __restrict__ g1, const float* __restrict__ b1,
    const float* __restrict__ m1, const float* __restrict__ v1,
    const int* __restrict__ grid, float* __restrict__ f1, int n) {
    const int tid = threadIdx.x;
    const int lane = tid & 63;
    const int h = lane >> 5;        // ci half
    const int c = lane & 31;        // output channel
    const int vbase = blockIdx.x * 128 + (tid >> 6) * 32;

    int bb = 0, z0 = 0, y0 = 0, x0 = 0;
    const bool vok = (lane < 32) && (vbase + lane) < n;
    if (vok) {
        const int4 cc = ((const int4*)coors)[vbase + lane];
        bb = cc.x; z0 = cc.y; y0 = cc.z; x0 = cc.w;
    }

    float acc[32];
#pragma unroll
    for (int j = 0; j < 32; ++j) acc[j] = 0.f;

#pragma unroll 1
    for (int k = 0; k < 27; ++k) {
        int idx = -1;
        {
            const int z = z0 + (k / 9) - 1;
            const int y = y0 + ((k / 3) % 3) - 1;
            const int x = x0 + (k % 3) - 1;
            if (vok && (unsigned)z < ZD && (unsigned)y < YD && (unsigned)x < XD)
                idx = grid[((bb * ZD + z) * YD + y) * XD + x];
        }
        const unsigned long long mask = __ballot(idx >= 0);

        // weights: W1[k][ci][c], this lane needs ci in [h*8, h*8+8)
        const float* __restrict__ wk = W1 + k * (NCIN * NC1) + h * 8 * NC1 + c;
        float w[8];
#pragma unroll
        for (int i = 0; i < 8; ++i) w[i] = wk[i * NC1];

#pragma unroll
        for (int j = 0; j < 32; ++j) {
            if (mask & (1ull << j)) {
                const int id = __builtin_amdgcn_readlane(idx, j);
                const float4* fr = (const float4*)(feat + (size_t)id * NCIN + h * 8);
                const float4 a = fr[0], b = fr[1];
                float t0 = fmaf(a.x, w[0], fmaf(a.y, w[1], fmaf(a.z, w[2], a.w * w[3])));
                float t1 = fmaf(b.x, w[4], fmaf(b.y, w[5], fmaf(b.z, w[6], b.w * w[7])));
                acc[j] += t0 + t1;
            }
        }
    }

    const float sc = g1[c] * rsqrtf(v1[c] + BN_EPS);
    const float sb = b1[c] - m1[c] * sc;
#pragma unroll
    for (int j = 0; j < 32; ++j) {
        const float s = acc[j] + __shfl_xor(acc[j], 32);
        const int vi = vbase + j;
        if (h == 0 && vi < n)
            f1[(size_t)vi * NC1 + c] = fmaxf(fmaf(s, sc, sb), 0.f);
    }
}

// wave = 32 output voxels, lane = output channel (64). acc[32] + w[32] ~ 85 VGPRs.
__global__ __launch_bounds__(256, 5) void conv2_k(
    const float* __restrict__ f1, const int* __restrict__ ocoors,
    const float* __restrict__ W2,
    const float* __restrict__ g2, const float* __restrict__ b2,
    const float* __restrict__ m2, const float* __restrict__ v2,
    const int* __restrict__ grid, float* __restrict__ out, int m) {
    const int tid = threadIdx.x;
    const int lane = tid & 63;
    const int vbase = blockIdx.x * 128 + (tid >> 6) * 32;

    int bb = 0, z0 = 0, y0 = 0, x0 = 0;
    const bool vok = (lane < 32) && (vbase + lane) < m;
    if (vok) {
        const int4 cc = ((const int4*)ocoors)[vbase + lane];
        bb = cc.x; z0 = cc.y * 2; y0 = cc.z * 2 - 1; x0 = cc.w * 2 - 1;
    }

    float acc[32];
#pragma unroll
    for (int j = 0; j < 32; ++j) acc[j] = 0.f;

#pragma unroll 1
    for (int k = 0; k < 27; ++k) {
        int idx = -1;
        {
            const int z = z0 + k / 9;
            const int y = y0 + (k / 3) % 3;
            const int x = x0 + k % 3;
            if (vok && (unsigned)z < ZD && (unsigned)y < YD && (unsigned)x < XD)
                idx = grid[((bb * ZD + z) * YD + y) * XD + x];
        }
        const unsigned long long mask = __ballot(idx >= 0);

        // weights: W2[k][ci][lane] — coalesced dword loads, L1-resident
        const float* __restrict__ wk = W2 + k * (NC1 * NC2) + lane;
        float w[NC1];
#pragma unroll
        for (int ci = 0; ci < NC1; ++ci) w[ci] = wk[ci * NC2];

#pragma unroll
        for (int j = 0; j < 32; ++j) {
            if (mask & (1ull << j)) {
                const int id = __builtin_amdgcn_readlane(idx, j);
                const float4* fr = (const float4*)(f1 + (size_t)id * NC1);
                const float4 q0 = fr[0], q1 = fr[1], q2 = fr[2], q3 = fr[3];
                const float4 q4 = fr[4], q5 = fr[5], q6 = fr[6], q7 = fr[7];
                float t0 = fmaf(q0.x, w[0], fmaf(q0.y, w[1], fmaf(q0.z, w[2], q0.w * w[3])));
                float t1 = fmaf(q1.x, w[4], fmaf(q1.y, w[5], fmaf(q1.z, w[6], q1.w * w[7])));
                float t2 = fmaf(q2.x, w[8], fmaf(q2.y, w[9], fmaf(q2.z, w[10], q2.w * w[11])));
                float t3 = fmaf(q3.x, w[12], fmaf(q3.y, w[13], fmaf(q3.z, w[14], q3.w * w[15])));
                float t4 = fmaf(q4.x, w[16], fmaf(q4.y, w[17], fmaf(q4.z, w[18], q4.w * w[19])));
                float t5 = fmaf(q5.x, w[20], fmaf(q5.y, w[21], fmaf(q5.z, w[22], q5.w * w[23])));
                float t6 = fmaf(q6.x, w[24], fmaf(q6.y, w[25], fmaf(q6.z, w[26], q6.w * w[27])));
                float t7 = fmaf(q7.x, w[28], fmaf(q7.y, w[29], fmaf(q7.z, w[30], q7.w * w[31])));
                acc[j] += ((t0 + t1) + (t2 + t3)) + ((t4 + t5) + (t6 + t7));
            }
        }
    }

    const float sc = g2[lane] * rsqrtf(v2[lane] + BN_EPS);
    const float sb = b2[lane] - m2[lane] * sc;
#pragma unroll
    for (int j = 0; j < 32; ++j) {
        const int vi = vbase + j;
        if (vi < m)
            out[(size_t)vi * NC2 + lane] = fmaxf(fmaf(acc[j], sc, sb), 0.f);
    }
}

// out_coors passthrough (as float values) + batch_size
__global__ __launch_bounds__(256) void tail_k(const int* __restrict__ oc,
                                              const int* __restrict__ bs,
                                              float* __restrict__ out, int m4) {
    int i = blockIdx.x * 256 + threadIdx.x;
    if (i < m4) out[i] = (float)oc[i];
    if (i == m4) out[m4] = (float)bs[0];
}

extern "C" void kernel_launch(void* const* d_in, const int* in_sizes, int n_in,
                              void* d_out, int out_size, void* d_ws, size_t ws_size,
                              hipStream_t stream) {
    const float* feat  = (const float*)d_in[0];
    const int*   coors = (const int*)d_in[1];
    const int*   ocoors= (const int*)d_in[2];
    const float* W1 = (const float*)d_in[3];
    const float* g1 = (const float*)d_in[4];
    const float* b1 = (const float*)d_in[5];
    const float* m1 = (const float*)d_in[6];
    const float* v1 = (const float*)d_in[7];
    const float* W2 = (const float*)d_in[8];
    const float* g2 = (const float*)d_in[9];
    const float* b2 = (const float*)d_in[10];
    const float* m2 = (const float*)d_in[11];
    const float* v2 = (const float*)d_in[12];
    const int*   bs = (const int*)d_in[13];

    const int n = in_sizes[0] / NCIN;
    const int m = in_sizes[2] / 4;

    const size_t GRID_N = (size_t)BD * ZD * YD * XD;
    int* grid = (int*)d_ws;
    float* f1 = (float*)((char*)d_ws + ((GRID_N * sizeof(int) + 255) & ~(size_t)255));

    hipMemsetAsync(grid, 0xFF, GRID_N * sizeof(int), stream);
    scatter_grid_k<<<(n + 255) / 256, 256, 0, stream>>>(coors, grid, n);
    conv1_k<<<(n + 127) / 128, 256, 0, stream>>>(feat, coors, W1, g1, b1, m1, v1, grid, f1, n);

    float* out = (float*)d_out;
    conv2_k<<<(m + 127) / 128, 256, 0, stream>>>(f1, ocoors, W2, g2, b2, m2, v2, grid, out, m);
    tail_k<<<(m * 4 + 1 + 255) / 256, 256, 0, stream>>>(ocoors, bs, out + (size_t)m * NC2, m * 4);
}

// Round 4
// 410.517 us; speedup vs baseline: 2.4374x; 1.2295x over previous
//
#include <hip/hip_runtime.h>

#define ZD 21
#define YD 256
#define XD 256
#define BD 2
#define NCIN 16
#define NC1 32
#define NC2 64
#define BN_EPS 1e-3f

typedef __attribute__((ext_vector_type(8))) short short8;
typedef __attribute__((ext_vector_type(4))) float floatx4;

__device__ inline void rne_split(float w, short& h, short& l) {
    unsigned b = __float_as_uint(w);
    unsigned hb = (b + 0x7FFFu + ((b >> 16) & 1u)) >> 16;
    float hf = __uint_as_float(hb << 16);
    float lf = w - hf;
    unsigned lb2 = __float_as_uint(lf);
    unsigned lb = (lb2 + 0x7FFFu + ((lb2 >> 16) & 1u)) >> 16;
    h = (short)hb; l = (short)lb;
}

__device__ inline void trunc_split(float v, short& h, short& l) {
    unsigned b = __float_as_uint(v);
    unsigned hb = b >> 16;
    float hf = __uint_as_float(hb << 16);
    float lf = v - hf;
    h = (short)hb;
    l = (short)(__float_as_uint(lf) >> 16);
}

__global__ __launch_bounds__(256) void scatter_grid_k(const int* __restrict__ coors,
                                                      int* __restrict__ grid, int n) {
    int i = blockIdx.x * 256 + threadIdx.x;
    if (i >= n) return;
    const int4 c = ((const int4*)coors)[i];   // [b, z, y, x]
    const int lin = ((c.x * ZD + c.y) * YD + c.z) * XD + c.w;
    grid[lin] = i;
}

// Pack W1 (pairs of offsets stacked to K=32) and W2 into MFMA B-fragment
// layout, hi/lo bf16 split. B-frag for 16x16x32: lane holds B[k=quad*8+j][n=lane&15].
__global__ __launch_bounds__(256) void pack_w_k(const float* __restrict__ W1,
                                                const float* __restrict__ W2,
                                                short* __restrict__ wp1,
                                                short* __restrict__ wp2) {
    int t = blockIdx.x * 256 + threadIdx.x;
    if (t < 14 * 2 * 512) {               // Wp1: [pair][cb][term][512]
        int pair = t / 1024, r = t % 1024, cb = r / 512, e = r % 512;
        int lane = e / 8, j = e % 8, quad = lane >> 4, kk = quad * 8 + j;
        int ko = pair * 2 + (kk >> 4), ci = kk & 15, co = cb * 16 + (lane & 15);
        float w = (ko < 27) ? W1[(ko * NCIN + ci) * NC1 + co] : 0.f;
        short h, l; rne_split(w, h, l);
        wp1[((pair * 2 + cb) * 2 + 0) * 512 + e] = h;
        wp1[((pair * 2 + cb) * 2 + 1) * 512 + e] = l;
    }
    int t2 = t - 14 * 2 * 512;
    if (t2 >= 0 && t2 < 27 * 4 * 512) {   // Wp2: [k][cb][term][512]
        int k = t2 / 2048, r = t2 % 2048, cb = r / 512, e = r % 512;
        int lane = e / 8, j = e % 8, ci = (lane >> 4) * 8 + j, co = cb * 16 + (lane & 15);
        float w = W2[(k * NC1 + ci) * NC2 + co];
        short h, l; rne_split(w, h, l);
        wp2[((k * 4 + cb) * 2 + 0) * 512 + e] = h;
        wp2[((k * 4 + cb) * 2 + 1) * 512 + e] = l;
    }
}

// wave = 16 output voxels (M=16). K=32 = two 3x3x3 offsets x 16 ci.
// A gathered per-lane from feat (fp32 -> hi/lo bf16 in-register).
__global__ __launch_bounds__(256, 4) void conv1_k(
    const float* __restrict__ feat, const int* __restrict__ coors,
    const short* __restrict__ wp1,
    const float* __restrict__ g1, const float* __restrict__ b1,
    const float* __restrict__ m1, const float* __restrict__ v1,
    const int* __restrict__ grid, unsigned short* __restrict__ f1hi,
    unsigned short* __restrict__ f1lo, int n) {
    const int tid = threadIdx.x;
    const int lane = tid & 63;
    const int quad = lane >> 4;
    const int mrow = lane & 15;
    const int vbase = blockIdx.x * 64 + (tid >> 6) * 16;

    int bb = 0, z0 = 0, y0 = 0, x0 = 0;
    const bool rok = (vbase + mrow) < n;
    if (rok) {
        const int4 cc = ((const int4*)coors)[vbase + mrow];
        bb = cc.x; z0 = cc.y; y0 = cc.z; x0 = cc.w;
    }

    floatx4 d0 = {0.f, 0.f, 0.f, 0.f}, d1 = {0.f, 0.f, 0.f, 0.f};
    const short8* __restrict__ wb = (const short8*)wp1;

#pragma unroll 1
    for (int pair = 0; pair < 14; ++pair) {
        const int ko = pair * 2 + (quad >> 1);
        int idx = -1;
        if (rok && ko < 27) {
            const int z = z0 + ko / 9 - 1;
            const int y = y0 + (ko / 3) % 3 - 1;
            const int x = x0 + ko % 3 - 1;
            if ((unsigned)z < ZD && (unsigned)y < YD && (unsigned)x < XD)
                idx = grid[((bb * ZD + z) * YD + y) * XD + x];
        }
        if (__ballot(idx >= 0) == 0) continue;

        short8 ahi = (short8)0, alo = (short8)0;
        if (idx >= 0) {
            const float4* fr = (const float4*)(feat + (size_t)idx * NCIN + (quad & 1) * 8);
            const float4 a = fr[0], b = fr[1];
            float v[8] = {a.x, a.y, a.z, a.w, b.x, b.y, b.z, b.w};
#pragma unroll
            for (int i = 0; i < 8; ++i) {
                short h, l; trunc_split(v[i], h, l);
                ahi[i] = h; alo[i] = l;
            }
        }

        const short8 b0h = wb[((pair * 2 + 0) * 2 + 0) * 64 + lane];
        const short8 b0l = wb[((pair * 2 + 0) * 2 + 1) * 64 + lane];
        const short8 b1h = wb[((pair * 2 + 1) * 2 + 0) * 64 + lane];
        const short8 b1l = wb[((pair * 2 + 1) * 2 + 1) * 64 + lane];
        d0 = __builtin_amdgcn_mfma_f32_16x16x32_bf16(ahi, b0h, d0, 0, 0, 0);
        d0 = __builtin_amdgcn_mfma_f32_16x16x32_bf16(ahi, b0l, d0, 0, 0, 0);
        d0 = __builtin_amdgcn_mfma_f32_16x16x32_bf16(alo, b0h, d0, 0, 0, 0);
        d1 = __builtin_amdgcn_mfma_f32_16x16x32_bf16(ahi, b1h, d1, 0, 0, 0);
        d1 = __builtin_amdgcn_mfma_f32_16x16x32_bf16(ahi, b1l, d1, 0, 0, 0);
        d1 = __builtin_amdgcn_mfma_f32_16x16x32_bf16(alo, b1h, d1, 0, 0, 0);
    }

    // C/D layout: col = lane&15 (channel), row = quad*4 + reg (voxel)
    const int col = lane & 15;
#pragma unroll
    for (int cb = 0; cb < 2; ++cb) {
        const floatx4 dd = cb ? d1 : d0;
        const int ch = cb * 16 + col;
        const float sc = g1[ch] * rsqrtf(v1[ch] + BN_EPS);
        const float sb = b1[ch] - m1[ch] * sc;
#pragma unroll
        for (int r = 0; r < 4; ++r) {
            const int v = vbase + quad * 4 + r;
            if (v < n) {
                const float o = fmaxf(fmaf(dd[r], sc, sb), 0.f);
                short h, l; trunc_split(o, h, l);
                f1hi[(size_t)v * NC1 + ch] = (unsigned short)h;
                f1lo[(size_t)v * NC1 + ch] = (unsigned short)l;
            }
        }
    }
}

// wave = 16 output voxels (M=16), N=64 (4 col-blocks), K=32 = ci per offset.
// A read directly from pre-split f1 hi/lo planes (already A-frag contiguous).
__global__ __launch_bounds__(256, 4) void conv2_k(
    const unsigned short* __restrict__ f1hi, const unsigned short* __restrict__ f1lo,
    const int* __restrict__ ocoors, const short* __restrict__ wp2,
    const float* __restrict__ g2, const float* __restrict__ b2,
    const float* __restrict__ m2, const float* __restrict__ v2,
    const int* __restrict__ grid, float* __restrict__ out, int m) {
    const int tid = threadIdx.x;
    const int lane = tid & 63;
    const int quad = lane >> 4;
    const int mrow = lane & 15;
    const int vbase = blockIdx.x * 64 + (tid >> 6) * 16;

    int bb = 0, z0 = 0, y0 = 0, x0 = 0;
    const bool rok = (vbase + mrow) < m;
    if (rok) {
        const int4 cc = ((const int4*)ocoors)[vbase + mrow];
        bb = cc.x; z0 = cc.y * 2; y0 = cc.z * 2 - 1; x0 = cc.w * 2 - 1;
    }

    floatx4 d[4];
#pragma unroll
    for (int cb = 0; cb < 4; ++cb) d[cb] = (floatx4){0.f, 0.f, 0.f, 0.f};
    const short8* __restrict__ wb = (const short8*)wp2;

#pragma unroll 1
    for (int k = 0; k < 27; ++k) {
        int idx = -1;
        if (rok) {
            const int z = z0 + k / 9;
            const int y = y0 + (k / 3) % 3;
            const int x = x0 + k % 3;
            if ((unsigned)z < ZD && (unsigned)y < YD && (unsigned)x < XD)
                idx = grid[((bb * ZD + z) * YD + y) * XD + x];
        }
        if (__ballot(idx >= 0) == 0) continue;

        short8 ahi = (short8)0, alo = (short8)0;
        if (idx >= 0) {
            ahi = *(const short8*)(f1hi + (size_t)idx * NC1 + quad * 8);
            alo = *(const short8*)(f1lo + (size_t)idx * NC1 + quad * 8);
        }

#pragma unroll
        for (int cb = 0; cb < 4; ++cb) {
            const short8 bh = wb[((k * 4 + cb) * 2 + 0) * 64 + lane];
            const short8 bl = wb[((k * 4 + cb) * 2 + 1) * 64 + lane];
            d[cb] = __builtin_amdgcn_mfma_f32_16x16x32_bf16(ahi, bh, d[cb], 0, 0, 0);
            d[cb] = __builtin_amdgcn_mfma_f32_16x16x32_bf16(ahi, bl, d[cb], 0, 0, 0);
            d[cb] = __builtin_amdgcn_mfma_f32_16x16x32_bf16(alo, bh, d[cb], 0, 0, 0);
        }
    }

    const int col = lane & 15;
#pragma unroll
    for (int cb = 0; cb < 4; ++cb) {
        const int ch = cb * 16 + col;
        const float sc = g2[ch] * rsqrtf(v2[ch] + BN_EPS);
        const float sb = b2[ch] - m2[ch] * sc;
#pragma unroll
        for (int r = 0; r < 4; ++r) {
            const int v = vbase + quad * 4 + r;
            if (v < m)
                out[(size_t)v * NC2 + ch] = fmaxf(fmaf(d[cb][r], sc, sb), 0.f);
        }
    }
}

// out_coors passthrough (as float values) + batch_size
__global__ __launch_bounds__(256) void tail_k(const int* __restrict__ oc,
                                              const int* __restrict__ bs,
                                              float* __restrict__ out, int m4) {
    int i = blockIdx.x * 256 + threadIdx.x;
    if (i < m4) out[i] = (float)oc[i];
    if (i == m4) out[m4] = (float)bs[0];
}

extern "C" void kernel_launch(void* const* d_in, const int* in_sizes, int n_in,
                              void* d_out, int out_size, void* d_ws, size_t ws_size,
                              hipStream_t stream) {
    const float* feat  = (const float*)d_in[0];
    const int*   coors = (const int*)d_in[1];
    const int*   ocoors= (const int*)d_in[2];
    const float* W1 = (const float*)d_in[3];
    const float* g1 = (const float*)d_in[4];
    const float* b1 = (const float*)d_in[5];
    const float* m1 = (const float*)d_in[6];
    const float* v1 = (const float*)d_in[7];
    const float* W2 = (const float*)d_in[8];
    const float* g2 = (const float*)d_in[9];
    const float* b2 = (const float*)d_in[10];
    const float* m2 = (const float*)d_in[11];
    const float* v2 = (const float*)d_in[12];
    const int*   bs = (const int*)d_in[13];

    const int n = in_sizes[0] / NCIN;
    const int m = in_sizes[2] / 4;

    const size_t GRID_N = (size_t)BD * ZD * YD * XD;
    char* ws = (char*)d_ws;
    int* grid = (int*)ws;
    size_t off = (GRID_N * sizeof(int) + 255) & ~(size_t)255;
    unsigned short* f1hi = (unsigned short*)(ws + off);
    off += ((size_t)n * NC1 * 2 + 255) & ~(size_t)255;
    unsigned short* f1lo = (unsigned short*)(ws + off);
    off += ((size_t)n * NC1 * 2 + 255) & ~(size_t)255;
    short* wp1 = (short*)(ws + off);
    off += (14 * 2 * 2 * 512 * 2 + 255) & ~(size_t)255;
    short* wp2 = (short*)(ws + off);

    hipMemsetAsync(grid, 0xFF, GRID_N * sizeof(int), stream);
    scatter_grid_k<<<(n + 255) / 256, 256, 0, stream>>>(coors, grid, n);
    pack_w_k<<<(14 * 1024 + 27 * 2048 + 255) / 256, 256, 0, stream>>>(W1, W2, wp1, wp2);

    conv1_k<<<(n + 63) / 64, 256, 0, stream>>>(feat, coors, wp1, g1, b1, m1, v1,
                                               grid, f1hi, f1lo, n);

    float* out = (float*)d_out;
    conv2_k<<<(m + 63) / 64, 256, 0, stream>>>(f1hi, f1lo, ocoors, wp2,
                                               g2, b2, m2, v2, grid, out, m);
    tail_k<<<(m * 4 + 1 + 255) / 256, 256, 0, stream>>>(ocoors, bs, out + (size_t)m * NC2, m * 4);
}

// Round 5
// 307.441 us; speedup vs baseline: 3.2546x; 1.3353x over previous
//
#include <hip/hip_runtime.h>

#define ZD 21
#define YD 256
#define XD 256
#define BD 2
#define NCIN 16
#define NC1 32
#define NC2 64
#define BN_EPS 1e-3f

typedef __attribute__((ext_vector_type(8))) short short8;
typedef __attribute__((ext_vector_type(4))) float floatx4;

__device__ inline void rne_split(float w, short& h, short& l) {
    unsigned b = __float_as_uint(w);
    unsigned hb = (b + 0x7FFFu + ((b >> 16) & 1u)) >> 16;
    float hf = __uint_as_float(hb << 16);
    float lf = w - hf;
    unsigned lb2 = __float_as_uint(lf);
    unsigned lb = (lb2 + 0x7FFFu + ((lb2 >> 16) & 1u)) >> 16;
    h = (short)hb; l = (short)lb;
}

__device__ inline void trunc_split(float v, short& h, short& l) {
    unsigned b = __float_as_uint(v);
    unsigned hb = b >> 16;
    float hf = __uint_as_float(hb << 16);
    float lf = v - hf;
    h = (short)hb;
    l = (short)(__float_as_uint(lf) >> 16);
}

__global__ __launch_bounds__(256) void scatter_grid_k(const int* __restrict__ coors,
                                                      int* __restrict__ grid, int n) {
    int i = blockIdx.x * 256 + threadIdx.x;
    if (i >= n) return;
    const int4 c = ((const int4*)coors)[i];   // [b, z, y, x]
    const int lin = ((c.x * ZD + c.y) * YD + c.z) * XD + c.w;
    grid[lin] = i;
}

// Pack W1 (pairs of offsets stacked to K=32) and W2 into MFMA B-fragment
// layout, hi/lo bf16 split. B-frag for 16x16x32: lane holds B[k=quad*8+j][n=lane&15].
__global__ __launch_bounds__(256) void pack_w_k(const float* __restrict__ W1,
                                                const float* __restrict__ W2,
                                                short* __restrict__ wp1,
                                                short* __restrict__ wp2) {
    int t = blockIdx.x * 256 + threadIdx.x;
    if (t < 14 * 2 * 512) {               // Wp1: [pair][cb][term][512]
        int pair = t / 1024, r = t % 1024, cb = r / 512, e = r % 512;
        int lane = e / 8, j = e % 8, quad = lane >> 4, kk = quad * 8 + j;
        int ko = pair * 2 + (kk >> 4), ci = kk & 15, co = cb * 16 + (lane & 15);
        float w = (ko < 27) ? W1[(ko * NCIN + ci) * NC1 + co] : 0.f;
        short h, l; rne_split(w, h, l);
        wp1[((pair * 2 + cb) * 2 + 0) * 512 + e] = h;
        wp1[((pair * 2 + cb) * 2 + 1) * 512 + e] = l;
    }
    int t2 = t - 14 * 2 * 512;
    if (t2 >= 0 && t2 < 27 * 4 * 512) {   // Wp2: [k][cb][term][512]
        int k = t2 / 2048, r = t2 % 2048, cb = r / 512, e = r % 512;
        int lane = e / 8, j = e % 8, ci = (lane >> 4) * 8 + j, co = cb * 16 + (lane & 15);
        float w = W2[(k * NC1 + ci) * NC2 + co];
        short h, l; rne_split(w, h, l);
        wp2[((k * 4 + cb) * 2 + 0) * 512 + e] = h;
        wp2[((k * 4 + cb) * 2 + 1) * 512 + e] = l;
    }
}

// wave = 64 output voxels (4 M-tiles of 16). K=32 = two 3x3x3 offsets x 16 ci.
// B fragments loaded once per pair and reused across 4 M-tiles.
__global__ __launch_bounds__(256, 3) void conv1_k(
    const float* __restrict__ feat, const int* __restrict__ coors,
    const short* __restrict__ wp1,
    const float* __restrict__ g1, const float* __restrict__ b1,
    const float* __restrict__ m1, const float* __restrict__ v1,
    const int* __restrict__ grid, unsigned short* __restrict__ f1hi,
    unsigned short* __restrict__ f1lo, int n) {
    const int tid = threadIdx.x;
    const int lane = tid & 63;
    const int quad = lane >> 4;
    const int mrow = lane & 15;
    const int vbase = blockIdx.x * 1024 + (tid >> 6) * 256;

    int bb[4], z0[4], y0[4], x0[4];
    bool rok[4];
#pragma unroll
    for (int mt = 0; mt < 4; ++mt) {
        const int v = vbase + mt * 16 + mrow;
        rok[mt] = v < n;
        bb[mt] = 0; z0[mt] = 0; y0[mt] = 0; x0[mt] = 0;
        if (rok[mt]) {
            const int4 cc = ((const int4*)coors)[v];
            bb[mt] = cc.x; z0[mt] = cc.y; y0[mt] = cc.z; x0[mt] = cc.w;
        }
    }

    floatx4 d[4][2];
#pragma unroll
    for (int mt = 0; mt < 4; ++mt)
#pragma unroll
        for (int cb = 0; cb < 2; ++cb) d[mt][cb] = (floatx4){0.f, 0.f, 0.f, 0.f};

    const short8* __restrict__ wb = (const short8*)wp1;
    const int ko_add = quad >> 1;     // this quad's offset within the pair
    const int ci_half = quad & 1;     // this quad's input-channel half

#pragma unroll 1
    for (int pair = 0; pair < 14; ++pair) {
        short8 ahi[4], alo[4];
        unsigned long long bm[4];
#pragma unroll
        for (int mt = 0; mt < 4; ++mt) {
            const int ko = pair * 2 + ko_add;
            int idx = -1;
            if (rok[mt] && ko < 27) {
                const int z = z0[mt] + ko / 9 - 1;
                const int y = y0[mt] + (ko / 3) % 3 - 1;
                const int x = x0[mt] + ko % 3 - 1;
                if ((unsigned)z < ZD && (unsigned)y < YD && (unsigned)x < XD)
                    idx = grid[((bb[mt] * ZD + z) * YD + y) * XD + x];
            }
            bm[mt] = __ballot(idx >= 0);
            ahi[mt] = (short8)0; alo[mt] = (short8)0;
            if (idx >= 0) {
                const float4* fr = (const float4*)(feat + (size_t)idx * NCIN + ci_half * 8);
                const float4 a = fr[0], b = fr[1];
                float v[8] = {a.x, a.y, a.z, a.w, b.x, b.y, b.z, b.w};
#pragma unroll
                for (int i = 0; i < 8; ++i) {
                    short h, l; trunc_split(v[i], h, l);
                    ahi[mt][i] = h; alo[mt][i] = l;
                }
            }
        }

        const short8 b0h = wb[((pair * 2 + 0) * 2 + 0) * 64 + lane];
        const short8 b0l = wb[((pair * 2 + 0) * 2 + 1) * 64 + lane];
        const short8 b1h = wb[((pair * 2 + 1) * 2 + 0) * 64 + lane];
        const short8 b1l = wb[((pair * 2 + 1) * 2 + 1) * 64 + lane];
#pragma unroll
        for (int mt = 0; mt < 4; ++mt) {
            if (bm[mt]) {
                d[mt][0] = __builtin_amdgcn_mfma_f32_16x16x32_bf16(ahi[mt], b0h, d[mt][0], 0, 0, 0);
                d[mt][0] = __builtin_amdgcn_mfma_f32_16x16x32_bf16(ahi[mt], b0l, d[mt][0], 0, 0, 0);
                d[mt][0] = __builtin_amdgcn_mfma_f32_16x16x32_bf16(alo[mt], b0h, d[mt][0], 0, 0, 0);
                d[mt][1] = __builtin_amdgcn_mfma_f32_16x16x32_bf16(ahi[mt], b1h, d[mt][1], 0, 0, 0);
                d[mt][1] = __builtin_amdgcn_mfma_f32_16x16x32_bf16(ahi[mt], b1l, d[mt][1], 0, 0, 0);
                d[mt][1] = __builtin_amdgcn_mfma_f32_16x16x32_bf16(alo[mt], b1h, d[mt][1], 0, 0, 0);
            }
        }
    }

    // C/D layout: col = lane&15 (channel), row = quad*4 + reg (voxel)
    const int col = lane & 15;
#pragma unroll
    for (int cb = 0; cb < 2; ++cb) {
        const int ch = cb * 16 + col;
        const float sc = g1[ch] * rsqrtf(v1[ch] + BN_EPS);
        const float sb = b1[ch] - m1[ch] * sc;
#pragma unroll
        for (int mt = 0; mt < 4; ++mt) {
#pragma unroll
            for (int r = 0; r < 4; ++r) {
                const int v = vbase + mt * 16 + quad * 4 + r;
                if (v < n) {
                    const float o = fmaxf(fmaf(d[mt][cb][r], sc, sb), 0.f);
                    short h, l; trunc_split(o, h, l);
                    f1hi[(size_t)v * NC1 + ch] = (unsigned short)h;
                    f1lo[(size_t)v * NC1 + ch] = (unsigned short)l;
                }
            }
        }
    }
}

// wave = 64 output voxels (4 M-tiles), N=64 (4 col-blocks), K=32 = ci per offset.
// A held for all 4 M-tiles; B loaded once per (k,cb) and reused 4x.
__global__ __launch_bounds__(256, 3) void conv2_k(
    const unsigned short* __restrict__ f1hi, const unsigned short* __restrict__ f1lo,
    const int* __restrict__ ocoors, const short* __restrict__ wp2,
    const float* __restrict__ g2, const float* __restrict__ b2,
    const float* __restrict__ m2, const float* __restrict__ v2,
    const int* __restrict__ grid, float* __restrict__ out, int m) {
    const int tid = threadIdx.x;
    const int lane = tid & 63;
    const int quad = lane >> 4;
    const int mrow = lane & 15;
    const int vbase = blockIdx.x * 1024 + (tid >> 6) * 256;

    int bb[4], z0[4], y0[4], x0[4];
    bool rok[4];
#pragma unroll
    for (int mt = 0; mt < 4; ++mt) {
        const int v = vbase + mt * 16 + mrow;
        rok[mt] = v < m;
        bb[mt] = 0; z0[mt] = 0; y0[mt] = 0; x0[mt] = 0;
        if (rok[mt]) {
            const int4 cc = ((const int4*)ocoors)[v];
            bb[mt] = cc.x; z0[mt] = cc.y * 2; y0[mt] = cc.z * 2 - 1; x0[mt] = cc.w * 2 - 1;
        }
    }

    floatx4 d[4][4];
#pragma unroll
    for (int mt = 0; mt < 4; ++mt)
#pragma unroll
        for (int cb = 0; cb < 4; ++cb) d[mt][cb] = (floatx4){0.f, 0.f, 0.f, 0.f};

    const short8* __restrict__ wb = (const short8*)wp2;

#pragma unroll 1
    for (int k = 0; k < 27; ++k) {
        const int dz = k / 9, dy = (k / 3) % 3, dx = k % 3;
        short8 ahi[4], alo[4];
        unsigned long long bm[4];
#pragma unroll
        for (int mt = 0; mt < 4; ++mt) {
            int idx = -1;
            const int z = z0[mt] + dz, y = y0[mt] + dy, x = x0[mt] + dx;
            if (rok[mt] && (unsigned)z < ZD && (unsigned)y < YD && (unsigned)x < XD)
                idx = grid[((bb[mt] * ZD + z) * YD + y) * XD + x];
            bm[mt] = __ballot(idx >= 0);
            ahi[mt] = (short8)0; alo[mt] = (short8)0;
            if (idx >= 0) {
                ahi[mt] = *(const short8*)(f1hi + (size_t)idx * NC1 + quad * 8);
                alo[mt] = *(const short8*)(f1lo + (size_t)idx * NC1 + quad * 8);
            }
        }

#pragma unroll
        for (int cb = 0; cb < 4; ++cb) {
            const short8 bh = wb[((k * 4 + cb) * 2 + 0) * 64 + lane];
            const short8 bl = wb[((k * 4 + cb) * 2 + 1) * 64 + lane];
#pragma unroll
            for (int mt = 0; mt < 4; ++mt) {
                if (bm[mt]) {
                    d[mt][cb] = __builtin_amdgcn_mfma_f32_16x16x32_bf16(ahi[mt], bh, d[mt][cb], 0, 0, 0);
                    d[mt][cb] = __builtin_amdgcn_mfma_f32_16x16x32_bf16(ahi[mt], bl, d[mt][cb], 0, 0, 0);
                    d[mt][cb] = __builtin_amdgcn_mfma_f32_16x16x32_bf16(alo[mt], bh, d[mt][cb], 0, 0, 0);
                }
            }
        }
    }

    const int col = lane & 15;
#pragma unroll
    for (int cb = 0; cb < 4; ++cb) {
        const int ch = cb * 16 + col;
        const float sc = g2[ch] * rsqrtf(v2[ch] + BN_EPS);
        const float sb = b2[ch] - m2[ch] * sc;
#pragma unroll
        for (int mt = 0; mt < 4; ++mt) {
#pragma unroll
            for (int r = 0; r < 4; ++r) {
                const int v = vbase + mt * 16 + quad * 4 + r;
                if (v < m)
                    out[(size_t)v * NC2 + ch] = fmaxf(fmaf(d[mt][cb][r], sc, sb), 0.f);
            }
        }
    }
}

// out_coors passthrough (as float values) + batch_size
__global__ __launch_bounds__(256) void tail_k(const int* __restrict__ oc,
                                              const int* __restrict__ bs,
                                              float* __restrict__ out, int m4) {
    int i = blockIdx.x * 256 + threadIdx.x;
    if (i < m4) out[i] = (float)oc[i];
    if (i == m4) out[m4] = (float)bs[0];
}

extern "C" void kernel_launch(void* const* d_in, const int* in_sizes, int n_in,
                              void* d_out, int out_size, void* d_ws, size_t ws_size,
                              hipStream_t stream) {
    const float* feat  = (const float*)d_in[0];
    const int*   coors = (const int*)d_in[1];
    const int*   ocoors= (const int*)d_in[2];
    const float* W1 = (const float*)d_in[3];
    const float* g1 = (const float*)d_in[4];
    const float* b1 = (const float*)d_in[5];
    const float* m1 = (const float*)d_in[6];
    const float* v1 = (const float*)d_in[7];
    const float* W2 = (const float*)d_in[8];
    const float* g2 = (const float*)d_in[9];
    const float* b2 = (const float*)d_in[10];
    const float* m2 = (const float*)d_in[11];
    const float* v2 = (const float*)d_in[12];
    const int*   bs = (const int*)d_in[13];

    const int n = in_sizes[0] / NCIN;
    const int m = in_sizes[2] / 4;

    const size_t GRID_N = (size_t)BD * ZD * YD * XD;
    char* ws = (char*)d_ws;
    int* grid = (int*)ws;
    size_t off = (GRID_N * sizeof(int) + 255) & ~(size_t)255;
    unsigned short* f1hi = (unsigned short*)(ws + off);
    off += ((size_t)n * NC1 * 2 + 255) & ~(size_t)255;
    unsigned short* f1lo = (unsigned short*)(ws + off);
    off += ((size_t)n * NC1 * 2 + 255) & ~(size_t)255;
    short* wp1 = (short*)(ws + off);
    off += (14 * 2 * 2 * 512 * 2 + 255) & ~(size_t)255;
    short* wp2 = (short*)(ws + off);

    hipMemsetAsync(grid, 0xFF, GRID_N * sizeof(int), stream);
    scatter_grid_k<<<(n + 255) / 256, 256, 0, stream>>>(coors, grid, n);
    pack_w_k<<<(14 * 1024 + 27 * 2048 + 255) / 256, 256, 0, stream>>>(W1, W2, wp1, wp2);

    conv1_k<<<(n + 1023) / 1024, 256, 0, stream>>>(feat, coors, wp1, g1, b1, m1, v1,
                                                   grid, f1hi, f1lo, n);

    float* out = (float*)d_out;
    conv2_k<<<(m + 1023) / 1024, 256, 0, stream>>>(f1hi, f1lo, ocoors, wp2,
                                                   g2, b2, m2, v2, grid, out, m);
    tail_k<<<(m * 4 + 1 + 255) / 256, 256, 0, stream>>>(ocoors, bs, out + (size_t)m * NC2, m * 4);
}